// Round 1
// baseline (402.004 us; speedup 1.0000x reference)
//
#include <hip/hip_runtime.h>

// S4 layer: B=8, L=4096, D=1024, N=128
//   xp = x @ Bw^T            (32768x1024)x(1024x128)   f16 MFMA
//   scan: h = A*h + u        chunked parallel scan, fp32
//   y  = hs @ Cw^T + x*Dp    (32768x128)x(128x1024)    f16 MFMA
//   final_state = broadcast(mean_b xp[:, L-1, :])      exact fp32

typedef _Float16 half8 __attribute__((ext_vector_type(8)));
typedef float f32x4 __attribute__((ext_vector_type(4)));

#define BDIM 8
#define LDIM 4096
#define DDIM 1024
#define NDIM 128
#define MTOT (BDIM * LDIM)      // 32768
#define CHUNK 128
#define NCHUNK (LDIM / CHUNK)   // 32
#define TOTCHUNK (BDIM * NCHUNK) // 256

// ---------------- GEMM1: xp[m][n] = sum_k x[m][k] * Bw[n][k] ----------------
// 128x128 tile, BK=32, 4 waves (2x2), each wave 64x64 via 4x4 16x16x32 MFMA.
__global__ __launch_bounds__(256) void gemm1(const float* __restrict__ x,
                                             const float* __restrict__ Bw,
                                             float* __restrict__ xp) {
    __shared__ _Float16 As[128 * 32];
    __shared__ _Float16 Bs[128 * 32];
    const int t = threadIdx.x;
    const int row0 = blockIdx.x * 128;
    const int wave = t >> 6, lane = t & 63;
    const int wr = (wave >> 1) * 64, wc = (wave & 1) * 64;
    const int lrow = lane & 15, kq = (lane >> 4) * 8;

    f32x4 acc[4][4] = {};

    for (int kk = 0; kk < 1024; kk += 32) {
        // stage A-tile (128 rows x 32 k, fp32 -> f16). 1024 float4s / 256 thr.
#pragma unroll
        for (int j = 0; j < 4; ++j) {
            int i = t + 256 * j;
            int r = i >> 3, c4 = i & 7;
            float4 v = *reinterpret_cast<const float4*>(&x[(row0 + r) * 1024 + kk + c4 * 4]);
            _Float16* dst = &As[r * 32 + c4 * 4];
            dst[0] = (_Float16)v.x; dst[1] = (_Float16)v.y;
            dst[2] = (_Float16)v.z; dst[3] = (_Float16)v.w;
        }
        // stage B-tile: Bw is [128 n][1024 k] row-major (already B^T form)
#pragma unroll
        for (int j = 0; j < 4; ++j) {
            int i = t + 256 * j;
            int r = i >> 3, c4 = i & 7;
            float4 v = *reinterpret_cast<const float4*>(&Bw[r * 1024 + kk + c4 * 4]);
            _Float16* dst = &Bs[r * 32 + c4 * 4];
            dst[0] = (_Float16)v.x; dst[1] = (_Float16)v.y;
            dst[2] = (_Float16)v.z; dst[3] = (_Float16)v.w;
        }
        __syncthreads();

        half8 bf[4];
#pragma unroll
        for (int ct = 0; ct < 4; ++ct)
            bf[ct] = *reinterpret_cast<const half8*>(&Bs[(wc + ct * 16 + lrow) * 32 + kq]);
#pragma unroll
        for (int rt = 0; rt < 4; ++rt) {
            half8 af = *reinterpret_cast<const half8*>(&As[(wr + rt * 16 + lrow) * 32 + kq]);
#pragma unroll
            for (int ct = 0; ct < 4; ++ct)
                acc[rt][ct] = __builtin_amdgcn_mfma_f32_16x16x32_f16(af, bf[ct], acc[rt][ct], 0, 0, 0);
        }
        __syncthreads();
    }

    // epilogue: C/D layout col=lane&15, row=(lane>>4)*4+i
    const int q4 = (lane >> 4) * 4;
#pragma unroll
    for (int rt = 0; rt < 4; ++rt) {
#pragma unroll
        for (int ct = 0; ct < 4; ++ct) {
            int col = wc + ct * 16 + lrow;
#pragma unroll
            for (int i = 0; i < 4; ++i)
                xp[(row0 + wr + rt * 16 + q4 + i) * 128 + col] = acc[rt][ct][i];
        }
    }
}

// ---------------- scan phase 1: per-chunk aggregates ----------------
// agg[chunk][n] = sum_{j} A^(127-j) * u[chunk*128+j][n]  (local scan end value)
__global__ void scan_agg(const float* __restrict__ xp, const float* __restrict__ logA,
                         float* __restrict__ agg) {
    const int chunk = blockIdx.x;   // b*32 + c
    const int n = threadIdx.x;      // 128 threads
    const float A = expf(logA[n]);
    const float* u = xp + chunk * CHUNK * 128 + n;
    float h = 0.f;
#pragma unroll 4
    for (int j = 0; j < CHUNK; ++j)
        h = fmaf(A, h, u[j * 128]);
    agg[chunk * 128 + n] = h;
}

// ---------------- scan phase 2: carries across chunks ----------------
__global__ void scan_carry(const float* __restrict__ agg, const float* __restrict__ logA,
                           float* __restrict__ hprev) {
    const int idx = blockIdx.x * blockDim.x + threadIdx.x;  // b*128+n, 1024 total
    const int b = idx >> 7, n = idx & 127;
    const float A128 = expf(128.f * logA[n]);   // decay over a full chunk
    float c = 0.f;
    for (int ch = 0; ch < NCHUNK; ++ch) {
        int g = (b * NCHUNK + ch) * 128 + n;
        hprev[g] = c;
        c = fmaf(A128, c, agg[g]);
    }
}

// ---------------- scan phase 3: final within-chunk scan, write hs (f16) ----------------
__global__ void scan_final(const float* __restrict__ xp, const float* __restrict__ logA,
                           const float* __restrict__ hprev, _Float16* __restrict__ hs) {
    const int chunk = blockIdx.x;
    const int n = threadIdx.x;
    const float A = expf(logA[n]);
    float h = hprev[chunk * 128 + n];
    const float* u = xp + chunk * CHUNK * 128 + n;
    _Float16* o = hs + chunk * CHUNK * 128 + n;
#pragma unroll 4
    for (int j = 0; j < CHUNK; ++j) {
        h = fmaf(A, h, u[j * 128]);
        o[j * 128] = (_Float16)h;
    }
}

// ---------------- GEMM2: y[m][d] = sum_n hs[m][n]*Cw[d][n] + x[m][d]*Dp[d] ----------------
__global__ __launch_bounds__(256) void gemm2(const _Float16* __restrict__ hs,
                                             const float* __restrict__ Cw,
                                             const float* __restrict__ x,
                                             const float* __restrict__ Dp,
                                             float* __restrict__ y) {
    __shared__ _Float16 As[128 * 32];
    __shared__ _Float16 Bs[128 * 32];
    const int t = threadIdx.x;
    const int row0 = blockIdx.x * 128;
    const int col0 = blockIdx.y * 128;
    const int wave = t >> 6, lane = t & 63;
    const int wr = (wave >> 1) * 64, wc = (wave & 1) * 64;
    const int lrow = lane & 15, kq = (lane >> 4) * 8;

    f32x4 acc[4][4] = {};

    for (int kk = 0; kk < 128; kk += 32) {
        // stage A-tile: hs already f16; 512 16B-chunks / 256 thr
#pragma unroll
        for (int j = 0; j < 2; ++j) {
            int i = t + 256 * j;
            int r = i >> 2, c8 = i & 3;
            *reinterpret_cast<half8*>(&As[r * 32 + c8 * 8]) =
                *reinterpret_cast<const half8*>(&hs[(row0 + r) * 128 + kk + c8 * 8]);
        }
        // stage B-tile: Cw is [1024 d][128 n] row-major (B^T form, k=n)
#pragma unroll
        for (int j = 0; j < 4; ++j) {
            int i = t + 256 * j;
            int r = i >> 3, c4 = i & 7;
            float4 v = *reinterpret_cast<const float4*>(&Cw[(col0 + r) * 128 + kk + c4 * 4]);
            _Float16* dst = &Bs[r * 32 + c4 * 4];
            dst[0] = (_Float16)v.x; dst[1] = (_Float16)v.y;
            dst[2] = (_Float16)v.z; dst[3] = (_Float16)v.w;
        }
        __syncthreads();

        half8 bf[4];
#pragma unroll
        for (int ct = 0; ct < 4; ++ct)
            bf[ct] = *reinterpret_cast<const half8*>(&Bs[(wc + ct * 16 + lrow) * 32 + kq]);
#pragma unroll
        for (int rt = 0; rt < 4; ++rt) {
            half8 af = *reinterpret_cast<const half8*>(&As[(wr + rt * 16 + lrow) * 32 + kq]);
#pragma unroll
            for (int ct = 0; ct < 4; ++ct)
                acc[rt][ct] = __builtin_amdgcn_mfma_f32_16x16x32_f16(af, bf[ct], acc[rt][ct], 0, 0, 0);
        }
        __syncthreads();
    }

    const int q4 = (lane >> 4) * 4;
#pragma unroll
    for (int rt = 0; rt < 4; ++rt) {
#pragma unroll
        for (int ct = 0; ct < 4; ++ct) {
            int col = col0 + wc + ct * 16 + lrow;
            float dpv = Dp[col];
#pragma unroll
            for (int i = 0; i < 4; ++i) {
                int row = row0 + wr + rt * 16 + q4 + i;
                y[row * 1024 + col] = acc[rt][ct][i] + x[row * 1024 + col] * dpv;
            }
        }
    }
}

// ---------------- final_state: exact fp32, out[b][n] = mean_b' dot(x[b',L-1,:], Bw[n,:]) ----------------
__global__ __launch_bounds__(256) void final_state_k(const float* __restrict__ x,
                                                     const float* __restrict__ Bw,
                                                     float* __restrict__ out) {
    const int n = blockIdx.x;   // 128 blocks
    const int t = threadIdx.x;  // 256 threads
    float s = 0.f;
    for (int b = 0; b < BDIM; ++b) {
        const float* xr = x + ((size_t)b * LDIM + (LDIM - 1)) * DDIM;
        const float* br = Bw + n * DDIM;
        for (int k = t; k < DDIM; k += 256)
            s = fmaf(xr[k], br[k], s);
    }
    __shared__ float red[256];
    red[t] = s;
    __syncthreads();
    for (int off = 128; off > 0; off >>= 1) {
        if (t < off) red[t] += red[t + off];
        __syncthreads();
    }
    if (t == 0) {
        float v = red[0] * 0.125f;
        for (int b = 0; b < BDIM; ++b)
            out[(size_t)MTOT * DDIM + b * NDIM + n] = v;
    }
}

extern "C" void kernel_launch(void* const* d_in, const int* in_sizes, int n_in,
                              void* d_out, int out_size, void* d_ws, size_t ws_size,
                              hipStream_t stream) {
    const float* x    = (const float*)d_in[0];   // (8, 4096, 1024)
    const float* Bw   = (const float*)d_in[1];   // (128, 1024)
    const float* Cw   = (const float*)d_in[2];   // (1024, 128)
    const float* logA = (const float*)d_in[3];   // (128,)
    const float* Dp   = (const float*)d_in[4];   // (1024,)
    float* out = (float*)d_out;                  // y (33554432) + final_state (1024)

    char* ws = (char*)d_ws;
    float*    xp    = (float*)   (ws);                         // 16,777,216 B
    _Float16* hs    = (_Float16*)(ws + 16777216);              //  8,388,608 B
    float*    agg   = (float*)   (ws + 16777216 + 8388608);    //    131,072 B
    float*    hprev = (float*)   (ws + 16777216 + 8388608 + 131072); // 131,072 B

    gemm1<<<MTOT / 128, 256, 0, stream>>>(x, Bw, xp);
    scan_agg<<<TOTCHUNK, 128, 0, stream>>>(xp, logA, agg);
    scan_carry<<<4, 256, 0, stream>>>(agg, logA, hprev);
    scan_final<<<TOTCHUNK, 128, 0, stream>>>(xp, logA, hprev, hs);
    gemm2<<<dim3(MTOT / 128, DDIM / 128), 256, 0, stream>>>(hs, Cw, x, Dp, out);
    final_state_k<<<NDIM, 256, 0, stream>>>(x, Bw, out);
}

// Round 2
// 329.669 us; speedup vs baseline: 1.2194x; 1.2194x over previous
//
#include <hip/hip_runtime.h>

// S4 layer: B=8, L=4096, D=1024, N=128
// R2: DMA-staged GEMMs + LDS-transpose coalesced epilogue in GEMM2.
//   prep:  final_state (exact fp32) + Bw,Cw -> f16
//   gemm1: xp = x @ Bw^T   (512 blocks of 64x128, BK=32, f16 MFMA)
//   scan:  3-phase chunked parallel scan (fp32)
//   gemm2: y = hs @ Cw^T + x*Dp  (2048 blocks of 128x128, K=128 single shot)

typedef _Float16 half8 __attribute__((ext_vector_type(8)));
typedef _Float16 half4 __attribute__((ext_vector_type(4)));
typedef float f32x4 __attribute__((ext_vector_type(4)));

#define BDIM 8
#define LDIM 4096
#define DDIM 1024
#define NDIM 128
#define MTOT (BDIM * LDIM)       // 32768
#define CHUNK 128
#define NCHUNK (LDIM / CHUNK)    // 32
#define TOTCHUNK (BDIM * NCHUNK) // 256

__device__ __forceinline__ void dma16(const void* g, void* l) {
    __builtin_amdgcn_global_load_lds((const __attribute__((address_space(1))) void*)g,
                                     (__attribute__((address_space(3))) void*)l, 16, 0, 0);
}

// ---------------- prep: final_state + convert Bw,Cw to f16 ----------------
__global__ __launch_bounds__(256) void prep(const float* __restrict__ x,
                                            const float* __restrict__ Bw,
                                            const float* __restrict__ Cw,
                                            _Float16* __restrict__ Bwh,
                                            _Float16* __restrict__ Cwh,
                                            float* __restrict__ out) {
    const int blk = blockIdx.x;
    const int t = threadIdx.x;
    if (blk < 128) {
        // final_state: out[b][n] = mean_b' dot(x[b',L-1,:], Bw[n,:])   (exact fp32)
        const int n = blk;
        float s = 0.f;
        const float* br = Bw + n * DDIM;
        for (int b = 0; b < BDIM; ++b) {
            const float* xr = x + ((size_t)b * LDIM + (LDIM - 1)) * DDIM;
            for (int k = t; k < DDIM; k += 256)
                s = fmaf(xr[k], br[k], s);
        }
        __shared__ float red[256];
        red[t] = s;
        __syncthreads();
        for (int off = 128; off > 0; off >>= 1) {
            if (t < off) red[t] += red[t + off];
            __syncthreads();
        }
        if (t == 0) {
            float v = red[0] * 0.125f;
            for (int b = 0; b < BDIM; ++b)
                out[(size_t)MTOT * DDIM + b * NDIM + n] = v;
        }
    } else {
        // convert 262144 fp32 (Bw 131072 then Cw 131072) to f16; 64 blocks x 4096 elems
        const int base = (blk - 128) * 4096;
#pragma unroll
        for (int j = 0; j < 4; ++j) {
            int e = base + j * 1024 + t * 4;
            const float* src;
            _Float16* dst;
            if (e < 131072) { src = Bw + e; dst = Bwh + e; }
            else            { src = Cw + (e - 131072); dst = Cwh + (e - 131072); }
            float4 v = *reinterpret_cast<const float4*>(src);
            half4 h = { (_Float16)v.x, (_Float16)v.y, (_Float16)v.z, (_Float16)v.w };
            *reinterpret_cast<half4*>(dst) = h;
        }
    }
}

// ---------------- GEMM1: xp[m][n] = sum_k x[m][k] * Bw[n][k] ----------------
// 64x128 tile, BK=32, 4 waves (2x2: 32x64 each, 2x4 frags). Grid 512.
__global__ __launch_bounds__(256) void gemm1(const float* __restrict__ x,
                                             const _Float16* __restrict__ Bwh,
                                             float* __restrict__ xp) {
    __shared__ _Float16 As[64 * 32];    // 4 KB
    __shared__ _Float16 Bs[128 * 32];   // 8 KB
    const int t = threadIdx.x;
    const int row0 = blockIdx.x * 64;
    const int wave = t >> 6, lane = t & 63;
    const int wr = (wave >> 1) * 32, wc = (wave & 1) * 64;
    const int lrow = lane & 15, kq = (lane >> 4) * 8;

    f32x4 acc[2][4] = {};

    for (int kk = 0; kk < DDIM; kk += 32) {
        // A-tile: 64x32 fp32 -> f16, 2 float4 per thread, packed ds_write_b64
#pragma unroll
        for (int j = 0; j < 2; ++j) {
            int i = t + 256 * j;
            int r = i >> 3, c4 = i & 7;
            float4 v = *reinterpret_cast<const float4*>(&x[(row0 + r) * DDIM + kk + c4 * 4]);
            half4 h = { (_Float16)v.x, (_Float16)v.y, (_Float16)v.z, (_Float16)v.w };
            *reinterpret_cast<half4*>(&As[r * 32 + c4 * 4]) = h;
        }
        // B-tile: 128x32 f16 via DMA (2 insts/wave)
#pragma unroll
        for (int inst = 0; inst < 2; ++inst) {
            int s = inst * 256 + t;
            int r = s >> 2, c8 = s & 3;
            dma16(&Bwh[r * DDIM + kk + c8 * 8], &Bs[(inst * 256 + wave * 64) * 8]);
        }
        __syncthreads();

        half8 bf[4];
#pragma unroll
        for (int ct = 0; ct < 4; ++ct)
            bf[ct] = *reinterpret_cast<const half8*>(&Bs[(wc + ct * 16 + lrow) * 32 + kq]);
#pragma unroll
        for (int rt = 0; rt < 2; ++rt) {
            half8 af = *reinterpret_cast<const half8*>(&As[(wr + rt * 16 + lrow) * 32 + kq]);
#pragma unroll
            for (int ct = 0; ct < 4; ++ct)
                acc[rt][ct] = __builtin_amdgcn_mfma_f32_16x16x32_f16(af, bf[ct], acc[rt][ct], 0, 0, 0);
        }
        __syncthreads();
    }

    const int q4 = (lane >> 4) * 4;
#pragma unroll
    for (int rt = 0; rt < 2; ++rt)
#pragma unroll
        for (int ct = 0; ct < 4; ++ct) {
            int col = wc + ct * 16 + lrow;
#pragma unroll
            for (int i = 0; i < 4; ++i)
                xp[(row0 + wr + rt * 16 + q4 + i) * NDIM + col] = acc[rt][ct][i];
        }
}

// ---------------- scan phase 1: per-chunk aggregates ----------------
__global__ void scan_agg(const float* __restrict__ xp, const float* __restrict__ logA,
                         float* __restrict__ agg) {
    const int chunk = blockIdx.x;
    const int n = threadIdx.x;
    const float A = expf(logA[n]);
    const float* u = xp + chunk * CHUNK * NDIM + n;
    float h = 0.f;
#pragma unroll 4
    for (int j = 0; j < CHUNK; ++j)
        h = fmaf(A, h, u[j * NDIM]);
    agg[chunk * NDIM + n] = h;
}

// ---------------- scan phase 2: carries across chunks ----------------
__global__ void scan_carry(const float* __restrict__ agg, const float* __restrict__ logA,
                           float* __restrict__ hprev) {
    const int idx = blockIdx.x * blockDim.x + threadIdx.x;  // 1024
    const int b = idx >> 7, n = idx & 127;
    const float A128 = expf(128.f * logA[n]);
    float c = 0.f;
    for (int ch = 0; ch < NCHUNK; ++ch) {
        int g = (b * NCHUNK + ch) * NDIM + n;
        hprev[g] = c;
        c = fmaf(A128, c, agg[g]);
    }
}

// ---------------- scan phase 3: final scan, write hs (f16) ----------------
__global__ void scan_final(const float* __restrict__ xp, const float* __restrict__ logA,
                           const float* __restrict__ hprev, _Float16* __restrict__ hs) {
    const int chunk = blockIdx.x;
    const int n = threadIdx.x;
    const float A = expf(logA[n]);
    float h = hprev[chunk * NDIM + n];
    const float* u = xp + chunk * CHUNK * NDIM + n;
    _Float16* o = hs + chunk * CHUNK * NDIM + n;
#pragma unroll 4
    for (int j = 0; j < CHUNK; ++j) {
        h = fmaf(A, h, u[j * NDIM]);
        o[j * NDIM] = (_Float16)h;
    }
}

// ---------------- GEMM2: y[m][d] = sum_n hs[m][n]*Cw[d][n] + x[m][d]*Dp[d] ----------------
// 128x128 tile, K=128 single shot (4 LDS panels of [128][32]), DMA staging,
// LDS-transpose epilogue with coalesced float4 x-load / y-store.
#define BUFW 132
__global__ __launch_bounds__(256) void gemm2(const _Float16* __restrict__ hs,
                                             const _Float16* __restrict__ Cwh,
                                             const float* __restrict__ x,
                                             const float* __restrict__ Dp,
                                             float* __restrict__ y) {
    __shared__ char smem[65536];                 // panels; reused as epilogue buffer
    __shared__ __align__(16) float DpS[128];
    _Float16* hsP = (_Float16*)smem;             // 4 panels x [128][32] f16 (32 KB)
    _Float16* CsP = (_Float16*)(smem + 32768);   // 4 panels x [128][32] f16 (32 KB)

    const int t = threadIdx.x;
    const int row0 = blockIdx.x * 128;
    const int col0 = blockIdx.y * 128;
    const int wave = t >> 6, lane = t & 63;
    const int wr = (wave >> 1) * 64, wc = (wave & 1) * 64;
    const int lrow = lane & 15, kq = (lane >> 4) * 8;

    if (t < 128) DpS[t] = Dp[col0 + t];

    // DMA staging: slot s -> f16 offset s*8; kb=s>>9, r=(s&511)>>2, c8=s&3
#pragma unroll
    for (int inst = 0; inst < 8; ++inst) {
        int s = inst * 256 + t;
        int kb = s >> 9, r = (s & 511) >> 2, c8 = s & 3;
        void* ldst = &hsP[(inst * 256 + wave * 64) * 8];
        dma16(&hs[(row0 + r) * NDIM + kb * 32 + c8 * 8], ldst);
    }
#pragma unroll
    for (int inst = 0; inst < 8; ++inst) {
        int s = inst * 256 + t;
        int kb = s >> 9, r = (s & 511) >> 2, c8 = s & 3;
        void* ldst = &CsP[(inst * 256 + wave * 64) * 8];
        dma16(&Cwh[(col0 + r) * NDIM + kb * 32 + c8 * 8], ldst);
    }
    __syncthreads();

    f32x4 acc[4][4] = {};
#pragma unroll
    for (int kb = 0; kb < 4; ++kb) {
        half8 bf[4];
#pragma unroll
        for (int ct = 0; ct < 4; ++ct)
            bf[ct] = *reinterpret_cast<const half8*>(&CsP[kb * 4096 + (wc + ct * 16 + lrow) * 32 + kq]);
#pragma unroll
        for (int rt = 0; rt < 4; ++rt) {
            half8 af = *reinterpret_cast<const half8*>(&hsP[kb * 4096 + (wr + rt * 16 + lrow) * 32 + kq]);
#pragma unroll
            for (int ct = 0; ct < 4; ++ct)
                acc[rt][ct] = __builtin_amdgcn_mfma_f32_16x16x32_f16(af, bf[ct], acc[rt][ct], 0, 0, 0);
        }
    }

    // epilogue: two 64-row halves through LDS fp32 buffer [64][BUFW]
    float* buf = (float*)smem;
    const int q4 = (lane >> 4) * 4;
#pragma unroll
    for (int half_ = 0; half_ < 2; ++half_) {
        __syncthreads();
        if ((wr >> 6) == half_) {
#pragma unroll
            for (int rt = 0; rt < 4; ++rt)
#pragma unroll
                for (int ct = 0; ct < 4; ++ct) {
                    int col = wc + ct * 16 + lrow;
#pragma unroll
                    for (int i = 0; i < 4; ++i)
                        buf[(rt * 16 + q4 + i) * BUFW + col] = acc[rt][ct][i];
                }
        }
        __syncthreads();
#pragma unroll
        for (int j = 0; j < 8; ++j) {
            int idx = t + 256 * j;
            int row = idx >> 5, c4 = idx & 31;
            int grow = row0 + half_ * 64 + row;
            float4 a = *reinterpret_cast<const float4*>(&buf[row * BUFW + c4 * 4]);
            float4 xv = *reinterpret_cast<const float4*>(&x[(size_t)grow * DDIM + col0 + c4 * 4]);
            float4 dp = *reinterpret_cast<const float4*>(&DpS[c4 * 4]);
            float4 o;
            o.x = a.x + xv.x * dp.x;
            o.y = a.y + xv.y * dp.y;
            o.z = a.z + xv.z * dp.z;
            o.w = a.w + xv.w * dp.w;
            *reinterpret_cast<float4*>(&y[(size_t)grow * DDIM + col0 + c4 * 4]) = o;
        }
    }
}

extern "C" void kernel_launch(void* const* d_in, const int* in_sizes, int n_in,
                              void* d_out, int out_size, void* d_ws, size_t ws_size,
                              hipStream_t stream) {
    const float* x    = (const float*)d_in[0];   // (8, 4096, 1024)
    const float* Bw   = (const float*)d_in[1];   // (128, 1024)
    const float* Cw   = (const float*)d_in[2];   // (1024, 128)
    const float* logA = (const float*)d_in[3];   // (128,)
    const float* Dp   = (const float*)d_in[4];   // (1024,)
    float* out = (float*)d_out;                  // y (33554432) + final_state (1024)

    char* ws = (char*)d_ws;
    float*    xp    = (float*)   (ws);                       // 16,777,216 B
    _Float16* hs    = (_Float16*)(ws + 16777216);            //  8,388,608 B
    float*    agg   = (float*)   (ws + 25165824);            //    131,072 B
    float*    hprev = (float*)   (ws + 25296896);            //    131,072 B
    _Float16* Bwh   = (_Float16*)(ws + 25427968);            //    262,144 B
    _Float16* Cwh   = (_Float16*)(ws + 25690112);            //    262,144 B

    prep<<<192, 256, 0, stream>>>(x, Bw, Cw, Bwh, Cwh, out);
    gemm1<<<MTOT / 64, 256, 0, stream>>>(x, Bwh, xp);
    scan_agg<<<TOTCHUNK, 128, 0, stream>>>(xp, logA, agg);
    scan_carry<<<4, 256, 0, stream>>>(agg, logA, hprev);
    scan_final<<<TOTCHUNK, 128, 0, stream>>>(xp, logA, hprev, hs);
    gemm2<<<dim3(MTOT / 128, DDIM / 128), 256, 0, stream>>>(hs, Cwh, x, Dp, out);
}